// Round 13
// baseline (165.870 us; speedup 1.0000x reference)
//
#include <hip/hip_runtime.h>

#define FEAT 128              // elements per row (int8 row = 128 bytes)
#define NB 8                  // s-slice buckets == #XCDs
#define HB 256                // histogram/scatter blocks
#define NBPB 1600             // blocks per bucket in affinity edge kernel
#define CHN 25000             // nodes per LDS chunk (100000 B, CH=4)
#define CNT_SHIFT 24          // count in bits [24..31] of packed u32
#define SIM_SCALE 16384.0f    // 2^14 fixed point for (sim+2) in [0,3.0]
#define INV_SIM (1.0f/16384.0f)

typedef unsigned uv4 __attribute__((ext_vector_type(4)));
typedef unsigned short us4 __attribute__((ext_vector_type(4)));
typedef unsigned long long ull;

__device__ __forceinline__ int dot4(unsigned a, unsigned b, int c) {
#if __has_builtin(__builtin_amdgcn_sdot4)
    return __builtin_amdgcn_sdot4(a, b, c, false);
#else
    c += (int)(signed char)(a)        * (int)(signed char)(b);
    c += (int)(signed char)(a >> 8)   * (int)(signed char)(b >> 8);
    c += (int)(signed char)(a >> 16)  * (int)(signed char)(b >> 16);
    c += (int)(signed char)(a >> 24)  * (int)(signed char)(b >> 24);
    return c;
#endif
}

__device__ __forceinline__ int dot16(uv4 a, uv4 b) {
    int c = dot4(a.x, b.x, 0);
    c = dot4(a.y, b.y, c);
    c = dot4(a.z, b.z, c);
    return dot4(a.w, b.w, c);
}

// Kernel 1: int8 quantization, 32 lanes per row (proven r9).
__global__ void quantize_kernel(const float* __restrict__ feat,
                                unsigned* __restrict__ tab32,
                                float* __restrict__ invq,
                                int num_nodes) {
    const int sub = threadIdx.x & 31;
    const int hpb = blockDim.x >> 5;
    int n = blockIdx.x * hpb + (threadIdx.x >> 5);
    const int stride = gridDim.x * hpb;
    for (; n < num_nodes; n += stride) {
        const float4 v = *reinterpret_cast<const float4*>(feat + (size_t)n * FEAT + sub * 4);
        float am = fmaxf(fmaxf(fabsf(v.x), fabsf(v.y)), fmaxf(fabsf(v.z), fabsf(v.w)));
        am = fmaxf(am, __shfl_xor(am, 16, 64));
        am = fmaxf(am, __shfl_xor(am, 8, 64));
        am = fmaxf(am, __shfl_xor(am, 4, 64));
        am = fmaxf(am, __shfl_xor(am, 2, 64));
        am = fmaxf(am, __shfl_xor(am, 1, 64));
        const float sc = (am > 0.0f) ? (127.0f / am) : 0.0f;
        const int q0 = (int)rintf(v.x * sc);
        const int q1 = (int)rintf(v.y * sc);
        const int q2 = (int)rintf(v.z * sc);
        const int q3 = (int)rintf(v.w * sc);
        int nq = q0 * q0 + q1 * q1 + q2 * q2 + q3 * q3;
        nq += __shfl_xor(nq, 16, 64);
        nq += __shfl_xor(nq, 8, 64);
        nq += __shfl_xor(nq, 4, 64);
        nq += __shfl_xor(nq, 2, 64);
        nq += __shfl_xor(nq, 1, 64);
        tab32[(size_t)n * (FEAT / 4) + sub] =
            (unsigned)(q0 & 0xFF) | ((unsigned)(q1 & 0xFF) << 8) |
            ((unsigned)(q2 & 0xFF) << 16) | ((unsigned)(q3 & 0xFF) << 24);
        if (sub == 0)
            invq[n] = (nq > 0) ? (1.0f / sqrtf((float)nq)) : 0.0f;
    }
}

// Sort pass A: per-block histogram of s-slice buckets.
__global__ void hist_kernel(const int* __restrict__ ei,
                            unsigned* __restrict__ hist,
                            int num_edges, int slice, int chunk) {
    __shared__ unsigned h[NB];
    if (threadIdx.x < NB) h[threadIdx.x] = 0;
    __syncthreads();
    const int lo = blockIdx.x * chunk;
    const int hi = min(lo + chunk, num_edges);
    for (int e = lo + threadIdx.x; e < hi; e += blockDim.x)
        atomicAdd(&h[(unsigned)ei[e] / (unsigned)slice], 1u);
    __syncthreads();
    if (threadIdx.x < NB) hist[threadIdx.x * HB + blockIdx.x] = h[threadIdx.x];
}

// Sort pass B: single-block exclusive scan of hist (bucket-major).
__global__ void scan_kernel(unsigned* __restrict__ hist,
                            unsigned* __restrict__ qs,
                            int num_edges) {
    __shared__ unsigned part[256];
    const int t = threadIdx.x;
    unsigned v[8], sum = 0;
#pragma unroll
    for (int i = 0; i < 8; ++i) { v[i] = hist[t * 8 + i]; sum += v[i]; }
    part[t] = sum;
    __syncthreads();
    for (int off = 1; off < 256; off <<= 1) {
        const unsigned x = (t >= off) ? part[t - off] : 0u;
        __syncthreads();
        part[t] += x;
        __syncthreads();
    }
    unsigned run = part[t] - sum;
    if ((t & 31) == 0) qs[t >> 5] = run;
    if (t == 255) qs[NB] = part[255];
#pragma unroll
    for (int i = 0; i < 8; ++i) { const unsigned tmp = v[i]; hist[t * 8 + i] = run; run += tmp; }
}

// Sort pass C: warp-aggregated scatter — one LDS atomic per wave per bucket,
// lanes of a bucket write CONTIGUOUS sd positions (coalesced).
__global__ void scatter_kernel(const int* __restrict__ ei,
                               const unsigned* __restrict__ hist,
                               ull* __restrict__ sd,
                               int num_edges, int slice, int chunk) {
    __shared__ unsigned cnt[NB];
    if (threadIdx.x < NB) cnt[threadIdx.x] = hist[threadIdx.x * HB + blockIdx.x];
    __syncthreads();
    const int lane = threadIdx.x & 63;
    const ull lanebit = 1ull << lane;
    const int lo = blockIdx.x * chunk;
    const int hi = min(lo + chunk, num_edges);
    for (int e = lo + threadIdx.x; e < hi; e += blockDim.x) {
        const unsigned s = (unsigned)ei[e];
        const unsigned d = (unsigned)ei[(size_t)num_edges + e];
        const unsigned b = s / (unsigned)slice;
        const ull pair = (ull)s | ((ull)d << 32);
#pragma unroll
        for (int k = 0; k < NB; ++k) {
            const ull mask = __ballot(b == (unsigned)k);
            if (b == (unsigned)k) {
                const int leader = __ffsll((unsigned long long)mask) - 1;
                unsigned wbase = 0;
                if (lane == leader)
                    wbase = atomicAdd(&cnt[k], (unsigned)__popcll(mask));
                wbase = __shfl(wbase, leader, 64);
                sd[wbase + (unsigned)__popcll(mask & (lanebit - 1ull))] = pair;
            }
        }
    }
}

// Kernel 2: affinity edge kernel. Block bid%8 -> bucket q (round-robin
// blockIdx->XCD => bucket's s-slice stays resident in ONE XCD's L2).
// Static mapping, no atomics/barriers; wrong-mapping risk is perf-only.
__global__ void edge_i8_aff(const unsigned char* __restrict__ tab,
                            const ull* __restrict__ sd,
                            const float* __restrict__ invq,
                            unsigned short* __restrict__ sim,
                            const unsigned* __restrict__ qs,
                            int num_edges) {
    const int sub = threadIdx.x & 7;
    const int grp = threadIdx.x >> 3;          // 0..31
    const int q = blockIdx.x & (NB - 1);
    const int w = blockIdx.x >> 3;             // 0..NBPB-1
    const int pstart = (int)((qs[q] + 3u) >> 2);
    const int pend = (int)((qs[q + 1] + 3u) >> 2);
    const int npack = pend - pstart;
    if (npack <= 0) return;
    const int per = (npack + NBPB - 1) / NBPB;
    const int p0 = pstart + w * per;
    const int p1 = min(p0 + per, pend);

    for (int p = p0 + grp; p < p1; p += 32) {
        const int e0 = p * 4;
        if (e0 >= num_edges) continue;
        const bool full = (e0 + 4 <= num_edges);

        int s[4], d[4];
        if (full) {
            const ulonglong2 w0 = *(const ulonglong2*)(sd + e0);
            const ulonglong2 w1 = *(const ulonglong2*)(sd + e0 + 2);
            s[0] = (int)(unsigned)w0.x; d[0] = (int)(unsigned)(w0.x >> 32);
            s[1] = (int)(unsigned)w0.y; d[1] = (int)(unsigned)(w0.y >> 32);
            s[2] = (int)(unsigned)w1.x; d[2] = (int)(unsigned)(w1.x >> 32);
            s[3] = (int)(unsigned)w1.y; d[3] = (int)(unsigned)(w1.y >> 32);
        } else {
#pragma unroll
            for (int k = 0; k < 4; ++k) {
                const int e = min(e0 + k, num_edges - 1);
                const ull wv = sd[e];
                s[k] = (int)(unsigned)wv; d[k] = (int)(unsigned)(wv >> 32);
            }
        }

        uv4 a[4], b[4];
#pragma unroll
        for (int k = 0; k < 4; ++k) {
            a[k] = *(const uv4*)(tab + (size_t)s[k] * FEAT + sub * 16);
            b[k] = *(const uv4*)(tab + (size_t)d[k] * FEAT + sub * 16);
        }
        int pd[4];
#pragma unroll
        for (int k = 0; k < 4; ++k) pd[k] = dot16(a[k], b[k]);
#pragma unroll
        for (int k = 0; k < 4; ++k) {
            pd[k] += __shfl_xor(pd[k], 1, 64);
            pd[k] += __shfl_xor(pd[k], 2, 64);
            pd[k] += __shfl_xor(pd[k], 4, 64);
        }

        int myidx = s[0];
        if (sub == 1) myidx = d[0];
        else if (sub == 2) myidx = s[1];
        else if (sub == 3) myidx = d[1];
        else if (sub == 4) myidx = s[2];
        else if (sub == 5) myidx = d[2];
        else if (sub == 6) myidx = s[3];
        else if (sub == 7) myidx = d[3];

        const float msc = invq[myidx];
        const float prod = msc * __shfl_xor(msc, 1, 64);

        const int gb = (threadIdx.x & 63) & ~7;
        const float pr0 = __shfl(prod, gb + 0, 64);
        const float pr1 = __shfl(prod, gb + 2, 64);
        const float pr2 = __shfl(prod, gb + 4, 64);
        const float pr3 = __shfl(prod, gb + 6, 64);

        if (sub == 0) {
            us4 o;
            o.x = (unsigned short)((float)pd[0] * pr0 * SIM_SCALE + 32768.5f);
            o.y = (unsigned short)((float)pd[1] * pr1 * SIM_SCALE + 32768.5f);
            o.z = (unsigned short)((float)pd[2] * pr2 * SIM_SCALE + 32768.5f);
            o.w = (unsigned short)((float)pd[3] * pr3 * SIM_SCALE + 32768.5f);
            if (full) {
                *(us4*)(sim + e0) = o;
            } else {
                if (e0 < num_edges) sim[e0] = o.x;
                if (e0 + 1 < num_edges) sim[e0 + 1] = o.y;
                if (e0 + 2 < num_edges) sim[e0 + 2] = o.z;
                if (e0 + 3 < num_edges) sim[e0 + 3] = o.w;
            }
        }
    }
}

// Tier-B edge kernel (unsorted, reads ei) — r9's proven kernel.
__global__ void edge_i8_sim(const unsigned char* __restrict__ tab,
                            const int* __restrict__ ei,
                            const float* __restrict__ invq,
                            unsigned short* __restrict__ sim,
                            int num_edges, int aligned4) {
    const int sub = threadIdx.x & 7;
    const int gid = blockIdx.x * (blockDim.x >> 3) + (threadIdx.x >> 3);
    const int e0 = gid * 4;
    if (e0 >= num_edges) return;
    int s[4], d[4];
    const bool fast = aligned4 && (e0 + 4 <= num_edges);
    if (fast) {
        const uv4 si = *(const uv4*)(ei + e0);
        const uv4 di = *(const uv4*)(ei + (size_t)num_edges + e0);
        s[0] = (int)si.x; s[1] = (int)si.y; s[2] = (int)si.z; s[3] = (int)si.w;
        d[0] = (int)di.x; d[1] = (int)di.y; d[2] = (int)di.z; d[3] = (int)di.w;
    } else {
#pragma unroll
        for (int k = 0; k < 4; ++k) {
            const int e = min(e0 + k, num_edges - 1);
            s[k] = ei[e];
            d[k] = ei[(size_t)num_edges + e];
        }
    }
    uv4 a[4], b[4];
#pragma unroll
    for (int k = 0; k < 4; ++k) {
        a[k] = *(const uv4*)(tab + (size_t)s[k] * FEAT + sub * 16);
        b[k] = *(const uv4*)(tab + (size_t)d[k] * FEAT + sub * 16);
    }
    int pd[4];
#pragma unroll
    for (int k = 0; k < 4; ++k) pd[k] = dot16(a[k], b[k]);
#pragma unroll
    for (int k = 0; k < 4; ++k) {
        pd[k] += __shfl_xor(pd[k], 1, 64);
        pd[k] += __shfl_xor(pd[k], 2, 64);
        pd[k] += __shfl_xor(pd[k], 4, 64);
    }
    int myidx = s[0];
    if (sub == 1) myidx = d[0];
    else if (sub == 2) myidx = s[1];
    else if (sub == 3) myidx = d[1];
    else if (sub == 4) myidx = s[2];
    else if (sub == 5) myidx = d[2];
    else if (sub == 6) myidx = s[3];
    else if (sub == 7) myidx = d[3];
    const float msc = invq[myidx];
    const float prod = msc * __shfl_xor(msc, 1, 64);
    const int gb = (threadIdx.x & 63) & ~7;
    const float pr0 = __shfl(prod, gb + 0, 64);
    const float pr1 = __shfl(prod, gb + 2, 64);
    const float pr2 = __shfl(prod, gb + 4, 64);
    const float pr3 = __shfl(prod, gb + 6, 64);
    if (sub == 0) {
        us4 o;
        o.x = (unsigned short)((float)pd[0] * pr0 * SIM_SCALE + 32768.5f);
        o.y = (unsigned short)((float)pd[1] * pr1 * SIM_SCALE + 32768.5f);
        o.z = (unsigned short)((float)pd[2] * pr2 * SIM_SCALE + 32768.5f);
        o.w = (unsigned short)((float)pd[3] * pr3 * SIM_SCALE + 32768.5f);
        if (fast) {
            *(us4*)(sim + e0) = o;
        } else {
            if (e0 < num_edges) sim[e0] = o.x;
            if (e0 + 1 < num_edges) sim[e0 + 1] = o.y;
            if (e0 + 2 < num_edges) sim[e0 + 2] = o.z;
            if (e0 + 3 < num_edges) sim[e0 + 3] = o.w;
        }
    }
}

// Kernel 3: LDS aggregation sweep (use_sd: packed sorted array, else ei).
__global__ __launch_bounds__(1024)
void agg_kernel(const int* __restrict__ ei,
                const ull* __restrict__ sd,
                const unsigned short* __restrict__ sim,
                unsigned* __restrict__ acc,
                int num_edges, int num_nodes, int CH, int S, int use_sd) {
    __shared__ unsigned lds[CHN];
    const int slice = blockIdx.x / CH;
    const int chunk = blockIdx.x % CH;
    const int base = chunk * CHN;
    const int cn = min(CHN, num_nodes - base);

    for (int i = threadIdx.x; i < cn; i += blockDim.x) lds[i] = 0;
    __syncthreads();

    const int P = (num_edges + 3) >> 2;
    const int p0 = (int)((long long)P * slice / S);
    const int p1 = (int)((long long)P * (slice + 1) / S);

    for (int p = p0 + threadIdx.x; p < p1; p += blockDim.x) {
        const int e0 = p * 4;
        if (e0 + 3 < num_edges) {
            unsigned sv[4], dv[4];
            if (use_sd) {
                const ulonglong2 w0 = *(const ulonglong2*)(sd + e0);
                const ulonglong2 w1 = *(const ulonglong2*)(sd + e0 + 2);
                sv[0] = (unsigned)w0.x; dv[0] = (unsigned)(w0.x >> 32);
                sv[1] = (unsigned)w0.y; dv[1] = (unsigned)(w0.y >> 32);
                sv[2] = (unsigned)w1.x; dv[2] = (unsigned)(w1.x >> 32);
                sv[3] = (unsigned)w1.y; dv[3] = (unsigned)(w1.y >> 32);
            } else {
                const uv4 su = *(const uv4*)(ei + e0);
                const uv4 du = *(const uv4*)(ei + (size_t)num_edges + e0);
                sv[0] = su.x; sv[1] = su.y; sv[2] = su.z; sv[3] = su.w;
                dv[0] = du.x; dv[1] = du.y; dv[2] = du.z; dv[3] = du.w;
            }
            const us4 sm = *(const us4*)(sim + e0);
#pragma unroll
            for (int k = 0; k < 4; ++k) {
                const unsigned v = (1u << CNT_SHIFT) | (unsigned)sm[k];
                const unsigned cs = sv[k] - (unsigned)base;
                const unsigned cd = dv[k] - (unsigned)base;
                if (cs < (unsigned)cn) atomicAdd(&lds[cs], v);
                if (cd < (unsigned)cn) atomicAdd(&lds[cd], v);
            }
        } else {
            for (int k = 0; k < 4; ++k) {
                const int e = e0 + k;
                if (e < num_edges) {
                    unsigned sv, dv;
                    if (use_sd) {
                        const ull w = sd[e];
                        sv = (unsigned)w; dv = (unsigned)(w >> 32);
                    } else {
                        sv = (unsigned)ei[e]; dv = (unsigned)ei[(size_t)num_edges + e];
                    }
                    const unsigned v = (1u << CNT_SHIFT) | (unsigned)sim[e];
                    const unsigned cs = sv - (unsigned)base;
                    const unsigned cd = dv - (unsigned)base;
                    if (cs < (unsigned)cn) atomicAdd(&lds[cs], v);
                    if (cd < (unsigned)cn) atomicAdd(&lds[cd], v);
                }
            }
        }
    }
    __syncthreads();
    for (int i = threadIdx.x; i < cn; i += blockDim.x)
        acc[(size_t)slice * num_nodes + base + i] = lds[i];
}

// Tier-C fallback: fused global packed atomics.
__global__ void edge_i8_atomic(const unsigned char* __restrict__ tab,
                               const int* __restrict__ ei,
                               const float* __restrict__ invq,
                               unsigned* __restrict__ acc,
                               int num_edges, int aligned4) {
    const int sub = threadIdx.x & 7;
    const int gid = blockIdx.x * (blockDim.x >> 3) + (threadIdx.x >> 3);
    const int e0 = gid * 4;
    if (e0 >= num_edges) return;
    int s[4], d[4];
    const bool fast = aligned4 && (e0 + 4 <= num_edges);
    if (fast) {
        const uv4 si = *(const uv4*)(ei + e0);
        const uv4 di = *(const uv4*)(ei + (size_t)num_edges + e0);
        s[0] = (int)si.x; s[1] = (int)si.y; s[2] = (int)si.z; s[3] = (int)si.w;
        d[0] = (int)di.x; d[1] = (int)di.y; d[2] = (int)di.z; d[3] = (int)di.w;
    } else {
#pragma unroll
        for (int k = 0; k < 4; ++k) {
            const int e = min(e0 + k, num_edges - 1);
            s[k] = ei[e];
            d[k] = ei[(size_t)num_edges + e];
        }
    }
    uv4 a[4], b[4];
#pragma unroll
    for (int k = 0; k < 4; ++k) {
        a[k] = *(const uv4*)(tab + (size_t)s[k] * FEAT + sub * 16);
        b[k] = *(const uv4*)(tab + (size_t)d[k] * FEAT + sub * 16);
    }
    int pd[4];
#pragma unroll
    for (int k = 0; k < 4; ++k) pd[k] = dot16(a[k], b[k]);
#pragma unroll
    for (int k = 0; k < 4; ++k) {
        pd[k] += __shfl_xor(pd[k], 1, 64);
        pd[k] += __shfl_xor(pd[k], 2, 64);
        pd[k] += __shfl_xor(pd[k], 4, 64);
    }
    int myidx = s[0];
    if (sub == 1) myidx = d[0];
    else if (sub == 2) myidx = s[1];
    else if (sub == 3) myidx = d[1];
    else if (sub == 4) myidx = s[2];
    else if (sub == 5) myidx = d[2];
    else if (sub == 6) myidx = s[3];
    else if (sub == 7) myidx = d[3];
    int mydot = pd[0];
    if (sub >= 6) mydot = pd[3];
    else if (sub >= 4) mydot = pd[2];
    else if (sub >= 2) mydot = pd[1];
    const float msc = invq[myidx];
    const float prod = msc * __shfl_xor(msc, 1, 64);
    if (fast || (e0 + (sub >> 1)) < num_edges) {
        const unsigned pk = (1u << CNT_SHIFT) |
            (unsigned)((float)mydot * prod * SIM_SCALE + 32768.5f);
        atomicAdd(&acc[myidx], pk);
    }
}

// Kernel 4: decode across S slice planes.
__global__ void final_kernel(const unsigned* __restrict__ acc,
                             float* __restrict__ out,
                             int num_nodes, int S) {
    const int i = blockIdx.x * blockDim.x + threadIdx.x;
    if (i < num_nodes) {
        unsigned cnt = 0, fx = 0;
        for (int c = 0; c < S; ++c) {
            const unsigned x = acc[(size_t)c * num_nodes + i];
            cnt += x >> CNT_SHIFT;
            fx += x & ((1u << CNT_SHIFT) - 1u);
        }
        out[i] = cnt ? ((float)fx * INV_SIM - 2.0f * (float)cnt) / (float)cnt : 1.0f;
    }
}

extern "C" void kernel_launch(void* const* d_in, const int* in_sizes, int n_in,
                              void* d_out, int out_size, void* d_ws, size_t ws_size,
                              hipStream_t stream) {
    const float* feat = (const float*)d_in[0];
    const int* ei = (const int*)d_in[1];
    const int num_nodes = in_sizes[0] / FEAT;     // 100000
    const int num_edges = in_sizes[1] / 2;        // 1600000
    float* out = (float*)d_out;
    const int aligned4 = ((num_edges & 3) == 0) ? 1 : 0;
    const int slice = (num_nodes + NB - 1) / NB;  // 12500
    const int CH = (num_nodes + CHN - 1) / CHN;   // 4

    const size_t E4 = (size_t)((num_edges + 3) & ~3) + 4;
    const size_t sd_bytes = E4 * sizeof(ull);
    const size_t sim_bytes = E4 * sizeof(unsigned short);
    const size_t invq_bytes = (size_t)num_nodes * sizeof(float);
    const size_t tab_bytes = (size_t)num_nodes * FEAT;
    const size_t meta_bytes = (size_t)NB * HB * 4 + 128;   // hist + qs

    const size_t fixedA = sd_bytes + sim_bytes + invq_bytes + tab_bytes + meta_bytes;
    const size_t fixedB = sim_bytes + invq_bytes + tab_bytes;
    const size_t plane = (size_t)num_nodes * sizeof(unsigned);

    int SA = 0, SB = 0;
    if (ws_size > fixedA) SA = (int)(((ws_size - fixedA) / plane > 64) ? 64 : (ws_size - fixedA) / plane);
    if (ws_size > fixedB) SB = (int)(((ws_size - fixedB) / plane > 64) ? 64 : (ws_size - fixedB) / plane);

    if (SA >= 8 && aligned4) {
        // Tier A layout: [sd][sim][invq][tab][hist|qs][acc]
        ull* sd = (ull*)d_ws;
        unsigned short* sim = (unsigned short*)((char*)d_ws + sd_bytes);
        float* invq = (float*)((char*)d_ws + sd_bytes + sim_bytes);
        unsigned* tab32 = (unsigned*)((char*)d_ws + sd_bytes + sim_bytes + invq_bytes);
        unsigned* hist = (unsigned*)((char*)d_ws + sd_bytes + sim_bytes + invq_bytes + tab_bytes);
        unsigned* qs = hist + NB * HB;
        unsigned* acc = (unsigned*)((char*)d_ws + fixedA);
        const int S = SA;

        quantize_kernel<<<(num_nodes + 7) / 8, 256, 0, stream>>>(feat, tab32, invq, num_nodes);
        const int chunk = (num_edges + HB - 1) / HB;
        hist_kernel<<<HB, 256, 0, stream>>>(ei, hist, num_edges, slice, chunk);
        scan_kernel<<<1, 256, 0, stream>>>(hist, qs, num_edges);
        scatter_kernel<<<HB, 256, 0, stream>>>(ei, hist, sd, num_edges, slice, chunk);
        edge_i8_aff<<<NB * NBPB, 256, 0, stream>>>(
            (const unsigned char*)tab32, sd, invq, sim, qs, num_edges);
        agg_kernel<<<CH * S, 1024, 0, stream>>>(ei, sd, sim, acc, num_edges,
                                                num_nodes, CH, S, 1);
        final_kernel<<<(num_nodes + 255) / 256, 256, 0, stream>>>(acc, out, num_nodes, S);
    } else if (SB >= 8 && aligned4) {
        // Tier B layout: [sim][invq][tab][acc]  (r9 structure)
        unsigned short* sim = (unsigned short*)d_ws;
        float* invq = (float*)((char*)d_ws + sim_bytes);
        unsigned* tab32 = (unsigned*)((char*)d_ws + sim_bytes + invq_bytes);
        unsigned* acc = (unsigned*)((char*)d_ws + fixedB);
        const int S = SB;

        quantize_kernel<<<(num_nodes + 7) / 8, 256, 0, stream>>>(feat, tab32, invq, num_nodes);
        {
            const int epb = (256 / 8) * 4;
            const int blocks = (num_edges + epb - 1) / epb;
            edge_i8_sim<<<blocks, 256, 0, stream>>>(
                (const unsigned char*)tab32, ei, invq, sim, num_edges, aligned4);
        }
        agg_kernel<<<CH * S, 1024, 0, stream>>>(ei, (const ull*)d_ws /*unused*/, sim, acc,
                                                num_edges, num_nodes, CH, S, 0);
        final_kernel<<<(num_nodes + 255) / 256, 256, 0, stream>>>(acc, out, num_nodes, S);
    } else {
        // Tier C: fused atomics, single plane. [acc][invq][tab]
        unsigned* acc = (unsigned*)d_ws;
        float* invq = (float*)((char*)d_ws + plane);
        unsigned* tab32 = (unsigned*)((char*)d_ws + plane + invq_bytes);
        hipMemsetAsync(acc, 0, plane, stream);
        quantize_kernel<<<(num_nodes + 7) / 8, 256, 0, stream>>>(feat, tab32, invq, num_nodes);
        {
            const int epb = (256 / 8) * 4;
            const int blocks = (num_edges + epb - 1) / epb;
            edge_i8_atomic<<<blocks, 256, 0, stream>>>(
                (const unsigned char*)tab32, ei, invq, acc, num_edges, aligned4);
        }
        final_kernel<<<(num_nodes + 255) / 256, 256, 0, stream>>>(acc, out, num_nodes, 1);
    }
}

// Round 14
// 134.747 us; speedup vs baseline: 1.2310x; 1.2310x over previous
//
#include <hip/hip_runtime.h>

#define FEAT 128              // elements per row (int8 row = 128 bytes)
#define EPG 4                 // edges per 8-lane group
#define CHN 25000             // nodes per LDS chunk (100000 B static LDS, CH=4)
#define CNT_SHIFT 24          // count in bits [24..31] of packed u32
#define SIM_SCALE 16384.0f    // 2^14 fixed point for (sim+2) in [0,3.0] -> <= 49152 (u16)
#define INV_SIM (1.0f/16384.0f)
#define EPS 1e-8f

typedef unsigned uv4 __attribute__((ext_vector_type(4)));
typedef unsigned short us4 __attribute__((ext_vector_type(4)));

__device__ __forceinline__ int dot4(unsigned a, unsigned b, int c) {
#if __has_builtin(__builtin_amdgcn_sdot4)
    return __builtin_amdgcn_sdot4(a, b, c, false);
#else
    c += (int)(signed char)(a)        * (int)(signed char)(b);
    c += (int)(signed char)(a >> 8)   * (int)(signed char)(b >> 8);
    c += (int)(signed char)(a >> 16)  * (int)(signed char)(b >> 16);
    c += (int)(signed char)(a >> 24)  * (int)(signed char)(b >> 24);
    return c;
#endif
}

__device__ __forceinline__ int dot16(uv4 a, uv4 b) {
    int c = dot4(a.x, b.x, 0);
    c = dot4(a.y, b.y, c);
    c = dot4(a.z, b.z, c);
    return dot4(a.w, b.w, c);
}

// Kernel 1: int8 quantization, 32 lanes per row. Lane j loads float4 (16B),
// packs its own 4 int8 -> one u32 store. amax/norm reduced over the 32-group.
__global__ void quantize_kernel(const float* __restrict__ feat,
                                unsigned* __restrict__ tab32,
                                float* __restrict__ invq,
                                int num_nodes) {
    const int sub = threadIdx.x & 31;
    const int hpb = blockDim.x >> 5;           // rows per block pass
    int n = blockIdx.x * hpb + (threadIdx.x >> 5);
    const int stride = gridDim.x * hpb;
    for (; n < num_nodes; n += stride) {
        const float4 v = *reinterpret_cast<const float4*>(feat + (size_t)n * FEAT + sub * 4);
        float am = fmaxf(fmaxf(fabsf(v.x), fabsf(v.y)), fmaxf(fabsf(v.z), fabsf(v.w)));
        am = fmaxf(am, __shfl_xor(am, 16, 64));
        am = fmaxf(am, __shfl_xor(am, 8, 64));
        am = fmaxf(am, __shfl_xor(am, 4, 64));
        am = fmaxf(am, __shfl_xor(am, 2, 64));
        am = fmaxf(am, __shfl_xor(am, 1, 64));
        const float sc = (am > 0.0f) ? (127.0f / am) : 0.0f;
        const int q0 = (int)rintf(v.x * sc);
        const int q1 = (int)rintf(v.y * sc);
        const int q2 = (int)rintf(v.z * sc);
        const int q3 = (int)rintf(v.w * sc);
        int nq = q0 * q0 + q1 * q1 + q2 * q2 + q3 * q3;
        nq += __shfl_xor(nq, 16, 64);
        nq += __shfl_xor(nq, 8, 64);
        nq += __shfl_xor(nq, 4, 64);
        nq += __shfl_xor(nq, 2, 64);
        nq += __shfl_xor(nq, 1, 64);
        tab32[(size_t)n * (FEAT / 4) + sub] =
            (unsigned)(q0 & 0xFF) | ((unsigned)(q1 & 0xFF) << 8) |
            ((unsigned)(q2 & 0xFF) << 16) | ((unsigned)(q3 & 0xFF) << 24);
        if (sub == 0)
            invq[n] = (nq > 0) ? (1.0f / sqrtf((float)nq)) : 0.0f;
    }
}

// Kernel 2 (phase 1): per-edge cosine -> u16 fixed-point array. NO atomics.
__global__ void edge_i8_sim(const unsigned char* __restrict__ tab,
                            const int* __restrict__ ei,
                            const float* __restrict__ invq,
                            unsigned short* __restrict__ sim,
                            int num_edges, int aligned4) {
    const int sub = threadIdx.x & 7;
    const int gid = blockIdx.x * (blockDim.x >> 3) + (threadIdx.x >> 3);
    const int e0 = gid * EPG;
    if (e0 >= num_edges) return;

    int s[EPG], d[EPG];
    const bool fast = aligned4 && (e0 + EPG <= num_edges);
    if (fast) {
        const uv4 si = *(const uv4*)(ei + e0);
        const uv4 di = *(const uv4*)(ei + (size_t)num_edges + e0);
        s[0] = (int)si.x; s[1] = (int)si.y; s[2] = (int)si.z; s[3] = (int)si.w;
        d[0] = (int)di.x; d[1] = (int)di.y; d[2] = (int)di.z; d[3] = (int)di.w;
    } else {
#pragma unroll
        for (int k = 0; k < EPG; ++k) {
            const int e = min(e0 + k, num_edges - 1);
            s[k] = ei[e];
            d[k] = ei[(size_t)num_edges + e];
        }
    }

    uv4 a[EPG], b[EPG];
#pragma unroll
    for (int k = 0; k < EPG; ++k) {
        a[k] = *(const uv4*)(tab + (size_t)s[k] * FEAT + sub * 16);
        b[k] = *(const uv4*)(tab + (size_t)d[k] * FEAT + sub * 16);
    }

    int p[EPG];
#pragma unroll
    for (int k = 0; k < EPG; ++k) p[k] = dot16(a[k], b[k]);
#pragma unroll
    for (int k = 0; k < EPG; ++k) {
        p[k] += __shfl_xor(p[k], 1, 64);
        p[k] += __shfl_xor(p[k], 2, 64);
        p[k] += __shfl_xor(p[k], 4, 64);
    }

    int myidx = s[0];
    if (sub == 1) myidx = d[0];
    else if (sub == 2) myidx = s[1];
    else if (sub == 3) myidx = d[1];
    else if (sub == 4) myidx = s[2];
    else if (sub == 5) myidx = d[2];
    else if (sub == 6) myidx = s[3];
    else if (sub == 7) myidx = d[3];

    const float msc = invq[myidx];
    const float prod = msc * __shfl_xor(msc, 1, 64);   // invq_s * invq_d on lanes 2k

    const int gb = (threadIdx.x & 63) & ~7;
    const float pr0 = __shfl(prod, gb + 0, 64);
    const float pr1 = __shfl(prod, gb + 2, 64);
    const float pr2 = __shfl(prod, gb + 4, 64);
    const float pr3 = __shfl(prod, gb + 6, 64);

    if (sub == 0) {
        us4 o;
        o.x = (unsigned short)((float)p[0] * pr0 * SIM_SCALE + 32768.5f);
        o.y = (unsigned short)((float)p[1] * pr1 * SIM_SCALE + 32768.5f);
        o.z = (unsigned short)((float)p[2] * pr2 * SIM_SCALE + 32768.5f);
        o.w = (unsigned short)((float)p[3] * pr3 * SIM_SCALE + 32768.5f);
        *(us4*)(sim + e0) = o;
    }
}

// Kernel 3 (phase 2): LDS aggregation sweep. Block = (chunk, slice).
// 100 KB LDS table per block (1 block/CU); CH=4 chunks -> sweep = 4x edge list.
__global__ __launch_bounds__(1024)
void agg_kernel(const int* __restrict__ ei,
                const unsigned short* __restrict__ sim,
                unsigned* __restrict__ acc,
                int num_edges, int num_nodes, int CH, int S, int aligned4) {
    __shared__ unsigned lds[CHN];
    const int slice = blockIdx.x / CH;
    const int chunk = blockIdx.x % CH;
    const int base = chunk * CHN;
    const int cn = min(CHN, num_nodes - base);

    for (int i = threadIdx.x; i < cn; i += blockDim.x) lds[i] = 0;
    __syncthreads();

    const int P = (num_edges + 3) >> 2;                 // 4-edge packets
    const int p0 = (int)((long long)P * slice / S);
    const int p1 = (int)((long long)P * (slice + 1) / S);

    for (int p = p0 + threadIdx.x; p < p1; p += blockDim.x) {
        const int e0 = p * 4;
        if (aligned4 && (e0 + 3 < num_edges)) {
            const uv4 su = *(const uv4*)(ei + e0);
            const uv4 du = *(const uv4*)(ei + (size_t)num_edges + e0);
            const us4 sm = *(const us4*)(sim + e0);
#pragma unroll
            for (int k = 0; k < 4; ++k) {
                const unsigned v = (1u << CNT_SHIFT) | (unsigned)sm[k];
                const unsigned cs = (unsigned)((int)su[k] - base);
                const unsigned cd = (unsigned)((int)du[k] - base);
                if (cs < (unsigned)cn) atomicAdd(&lds[cs], v);
                if (cd < (unsigned)cn) atomicAdd(&lds[cd], v);
            }
        } else {
#pragma unroll
            for (int k = 0; k < 4; ++k) {
                const int e = e0 + k;
                if (e < num_edges) {
                    const unsigned v = (1u << CNT_SHIFT) | (unsigned)sim[e];
                    const unsigned cs = (unsigned)(ei[e] - base);
                    const unsigned cd = (unsigned)(ei[(size_t)num_edges + e] - base);
                    if (cs < (unsigned)cn) atomicAdd(&lds[cs], v);
                    if (cd < (unsigned)cn) atomicAdd(&lds[cd], v);
                }
            }
        }
    }
    __syncthreads();
    for (int i = threadIdx.x; i < cn; i += blockDim.x)
        acc[(size_t)slice * num_nodes + base + i] = lds[i];
}

// Fallback fused path: global packed atomics (used only if ws too small).
__global__ void edge_i8_atomic(const unsigned char* __restrict__ tab,
                               const int* __restrict__ ei,
                               const float* __restrict__ invq,
                               unsigned* __restrict__ acc,
                               int num_edges, int aligned4) {
    const int sub = threadIdx.x & 7;
    const int gid = blockIdx.x * (blockDim.x >> 3) + (threadIdx.x >> 3);
    const int e0 = gid * EPG;
    if (e0 >= num_edges) return;
    int s[EPG], d[EPG];
    const bool fast = aligned4 && (e0 + EPG <= num_edges);
    if (fast) {
        const uv4 si = *(const uv4*)(ei + e0);
        const uv4 di = *(const uv4*)(ei + (size_t)num_edges + e0);
        s[0] = (int)si.x; s[1] = (int)si.y; s[2] = (int)si.z; s[3] = (int)si.w;
        d[0] = (int)di.x; d[1] = (int)di.y; d[2] = (int)di.z; d[3] = (int)di.w;
    } else {
#pragma unroll
        for (int k = 0; k < EPG; ++k) {
            const int e = min(e0 + k, num_edges - 1);
            s[k] = ei[e];
            d[k] = ei[(size_t)num_edges + e];
        }
    }
    uv4 a[EPG], b[EPG];
#pragma unroll
    for (int k = 0; k < EPG; ++k) {
        a[k] = *(const uv4*)(tab + (size_t)s[k] * FEAT + sub * 16);
        b[k] = *(const uv4*)(tab + (size_t)d[k] * FEAT + sub * 16);
    }
    int p[EPG];
#pragma unroll
    for (int k = 0; k < EPG; ++k) p[k] = dot16(a[k], b[k]);
#pragma unroll
    for (int k = 0; k < EPG; ++k) {
        p[k] += __shfl_xor(p[k], 1, 64);
        p[k] += __shfl_xor(p[k], 2, 64);
        p[k] += __shfl_xor(p[k], 4, 64);
    }
    int myidx = s[0];
    if (sub == 1) myidx = d[0];
    else if (sub == 2) myidx = s[1];
    else if (sub == 3) myidx = d[1];
    else if (sub == 4) myidx = s[2];
    else if (sub == 5) myidx = d[2];
    else if (sub == 6) myidx = s[3];
    else if (sub == 7) myidx = d[3];
    int mydot = p[0];
    if (sub >= 6) mydot = p[3];
    else if (sub >= 4) mydot = p[2];
    else if (sub >= 2) mydot = p[1];
    const float msc = invq[myidx];
    const float prod = msc * __shfl_xor(msc, 1, 64);
    if (fast || (e0 + (sub >> 1)) < num_edges) {
        const unsigned pk = (1u << CNT_SHIFT) |
            (unsigned)((float)mydot * prod * SIM_SCALE + 32768.5f);
        atomicAdd(&acc[myidx], pk);
    }
}

// Kernel 4: decode across S slice planes.
__global__ void final_kernel(const unsigned* __restrict__ acc,
                             float* __restrict__ out,
                             int num_nodes, int S) {
    const int i = blockIdx.x * blockDim.x + threadIdx.x;
    if (i < num_nodes) {
        unsigned cnt = 0, fx = 0;
        for (int c = 0; c < S; ++c) {
            const unsigned x = acc[(size_t)c * num_nodes + i];
            cnt += x >> CNT_SHIFT;
            fx += x & ((1u << CNT_SHIFT) - 1u);
        }
        out[i] = cnt ? ((float)fx * INV_SIM - 2.0f * (float)cnt) / (float)cnt : 1.0f;
    }
}

extern "C" void kernel_launch(void* const* d_in, const int* in_sizes, int n_in,
                              void* d_out, int out_size, void* d_ws, size_t ws_size,
                              hipStream_t stream) {
    const float* feat = (const float*)d_in[0];
    const int* ei = (const int*)d_in[1];
    const int num_nodes = in_sizes[0] / FEAT;     // 100000
    const int num_edges = in_sizes[1] / 2;        // 1600000
    float* out = (float*)d_out;
    const int aligned4 = ((num_edges & 3) == 0) ? 1 : 0;

    // ws layout: [sim u16 padE] [invq f32 N] [tab i8 N*128] [acc u32 S*N]
    const size_t padE = (size_t)((num_edges + 3) & ~3) + 4;
    const size_t off_invq = padE * sizeof(unsigned short);
    const size_t off_tab = off_invq + (size_t)num_nodes * sizeof(float);
    const size_t off_acc = off_tab + (size_t)num_nodes * FEAT;

    unsigned short* sim = (unsigned short*)d_ws;
    float* invq = (float*)((char*)d_ws + off_invq);
    unsigned* tab32 = (unsigned*)((char*)d_ws + off_tab);
    unsigned* acc = (unsigned*)((char*)d_ws + off_acc);

    int S = 0;
    if (ws_size > off_acc) {
        const size_t avail = ws_size - off_acc;
        size_t smax = avail / ((size_t)num_nodes * sizeof(unsigned));
        S = (int)((smax > 64) ? 64 : smax);
    }
    const int CH = (num_nodes + CHN - 1) / CHN;   // 4 chunks at N=100000

    // quantize (always needed): 32 lanes/row, 8 rows per 256-thread block
    {
        const int hpb = 8;
        int blocks = (num_nodes + hpb - 1) / hpb;
        quantize_kernel<<<blocks, 256, 0, stream>>>(feat, tab32, invq, num_nodes);
    }

    if (S >= 8 && aligned4) {
        {
            const int epb = (256 / 8) * EPG;                  // 128 edges/block
            const int blocks = (num_edges + epb - 1) / epb;
            edge_i8_sim<<<blocks, 256, 0, stream>>>(
                (const unsigned char*)tab32, ei, invq, sim, num_edges, aligned4);
        }
        agg_kernel<<<CH * S, 1024, 0, stream>>>(ei, sim, acc, num_edges,
                                                num_nodes, CH, S, aligned4);
        final_kernel<<<(num_nodes + 255) / 256, 256, 0, stream>>>(acc, out, num_nodes, S);
    } else {
        hipMemsetAsync(acc, 0, (size_t)num_nodes * sizeof(unsigned), stream);
        {
            const int epb = (256 / 8) * EPG;
            const int blocks = (num_edges + epb - 1) / epb;
            edge_i8_atomic<<<blocks, 256, 0, stream>>>(
                (const unsigned char*)tab32, ei, invq, acc, num_edges, aligned4);
        }
        final_kernel<<<(num_nodes + 255) / 256, 256, 0, stream>>>(acc, out, num_nodes, 1);
    }
}